// Round 16
// baseline (149.849 us; speedup 1.0000x reference)
//
#include <hip/hip_runtime.h>

// OrthogonalBasisSelfAttention: B=2, L=2048, D=1024, H=16, DH=64, R=512, NUM_BASIS=6
// scores = q.(Wqp Wkp^T/sqrt(R)).k^T -> fold A_h (x log2e) into Wq'; S = qt.k^T (K=64).
// DCT bias + mask folded as rank-12 columns (qe/ke) into QK^T; softmax = exp2(ST).
// R16: ke fragments loaded direct-from-global (register-pipelined) -> LDS 32KB,
// 5 blocks/CU; k_pre0 merged into k_prep (Ah does its own per-chunk LDS transpose).

typedef unsigned short ushort_t;
typedef unsigned long long ull_t;
typedef __attribute__((ext_vector_type(8))) short bf16x8;   // 8 bf16 = 4 VGPR (MFMA A/B frag)
typedef __attribute__((ext_vector_type(4))) float f32x4;    // MFMA C/D frag

#define LOG2E 1.4426950408889634f
#define PI_F 3.14159265358979323846f

__device__ inline f32x4 mfma16(bf16x8 a, bf16x8 b, f32x4 c) {
  return __builtin_amdgcn_mfma_f32_16x16x32_bf16(a, b, c, 0, 0, 0);
}
__device__ inline void load_lds16(const void* g, void* l) {
  __builtin_amdgcn_global_load_lds((const __attribute__((address_space(1))) unsigned int*)g,
                                   (__attribute__((address_space(3))) unsigned int*)l, 16, 0, 0);
}
__device__ inline ushort_t f2bf(float f) {  // round-to-nearest-even
  union { float f; unsigned int u; } v; v.f = f;
  unsigned int u = v.u;
  return (ushort_t)((u + 0x7fffu + ((u >> 16) & 1u)) >> 16);
}
__device__ inline unsigned cvt_pk_bf16(float lo, float hi) {
  unsigned r;
  asm("v_cvt_pk_bf16_f32 %0, %1, %2" : "=v"(r) : "v"(lo), "v"(hi));
  return r;
}
#if __has_builtin(__builtin_amdgcn_exp2f)
__device__ inline float exp2_(float x) { return __builtin_amdgcn_exp2f(x); }
#else
__device__ inline float exp2_(float x) { return exp2f(x); }
#endif

// ---- k_prep: Ah (in-kernel kpw transpose, grid-front) + cvt + ke/qe tables ----
// blocks [0,64): Ah[h][d][d'] = sum_r qpw[h][d][r]*kpw[h][d'][r] * C  (r-chunked LDS transpose)
// blocks [64,6208): fp32->bf16 cvt (hidden / Wk / Wv)
// blocks [6208,6224): ke[b][m][32]; blocks [6224,6352): qe[h][q][32]
__global__ __launch_bounds__(256) void k_prep(
    const float* __restrict__ hidden, const float* __restrict__ Wk,
    const float* __restrict__ Wv, const float* __restrict__ qpw,
    const float* __restrict__ kpw, const float* __restrict__ coef,
    const float* __restrict__ maskp,
    ushort_t* __restrict__ hb, ushort_t* __restrict__ w3, float* __restrict__ Ah,
    ushort_t* __restrict__ ke, ushort_t* __restrict__ qe) {
  __shared__ float tile[64][65];
  const int blk = blockIdx.x, tid = threadIdx.x;
  if (blk < 64) {
    int h = blk >> 2, db = (blk & 3) * 16;
    int dp = tid & 63, d0 = db + (tid >> 6) * 4;
    float acc[4] = {0.f, 0.f, 0.f, 0.f};
    const float* kh = kpw + (size_t)h * 64 * 512;
    const float* qr = qpw + ((size_t)h * 64 + d0) * 512;
    for (int rc = 0; rc < 8; rc++) {
      __syncthreads();
      #pragma unroll
      for (int i = 0; i < 4; i++) {
        int idx = i * 256 + tid;              // 1024 float4 = 64 rows x 64 cols
        int d = idx >> 4, c4 = idx & 15;
        float4 v = *(const float4*)(kh + (size_t)d * 512 + rc * 64 + c4 * 4);
        *(float4*)(&tile[d][c4 * 4]) = v;
      }
      __syncthreads();
      for (int rr = 0; rr < 64; rr += 4) {
        float4 wk = *(const float4*)(&tile[dp][rr]);  // kpw[h][dp][rc*64+rr..+3]
        int r = rc * 64 + rr;
        #pragma unroll
        for (int i = 0; i < 4; i++) {
          float4 wq = *(const float4*)(qr + i * 512 + r);
          acc[i] += wq.x * wk.x + wq.y * wk.y + wq.z * wk.z + wq.w * wk.w;
        }
      }
    }
    #pragma unroll
    for (int i = 0; i < 4; i++)
      Ah[((size_t)h * 64 + d0 + i) * 64 + dp] = acc[i] * (0.044194173824159216f * LOG2E);
  } else if (blk < 6208) {
    const float* in;
    ushort_t* out;
    int base = blk - 64;
    if (base < 4096) { in = hidden; out = hb; }
    else if (base < 5120) { in = Wk; out = w3 + 1048576; base -= 4096; }
    else { in = Wv; out = w3 + 2097152; base -= 5120; }
    int i = (base * 256 + tid) * 4;
    float4 v = *(const float4*)(in + i);
    ull_t pk = (ull_t)f2bf(v.x) | ((ull_t)f2bf(v.y) << 16)
             | ((ull_t)f2bf(v.z) << 32) | ((ull_t)f2bf(v.w) << 48);
    *(ull_t*)(out + i) = pk;
  } else if (blk < 6224) {
    int i = (blk - 6208) * 256 + tid;      // 0..4095
    int bb = i >> 11, m = i & 2047;
    float base = PI_F * (float)m * (1.0f / 2047.0f);
    ushort_t row[32];
    row[0] = f2bf(1.0f);
    #pragma unroll
    for (int k = 1; k <= 5; k++) {
      float a = base * (float)k;
      row[2 * k - 1] = f2bf(cosf(a));
      row[2 * k]     = f2bf(sinf(a));
    }
    row[11] = f2bf(maskp[bb * 2048 + m] * LOG2E);
    #pragma unroll
    for (int j = 12; j < 32; j++) row[j] = 0;
    ull_t* dst = (ull_t*)(ke + ((size_t)(bb * 2048 + m)) * 32);
    #pragma unroll
    for (int j = 0; j < 4; j++) {
      ull_t pk = 0;
      #pragma unroll
      for (int e = 0; e < 4; e++) pk |= (ull_t)row[j * 4 + e] << (16 * e);
      dst[j] = pk;
    }
  } else {
    int i = (blk - 6224) * 256 + tid;      // 0..32767
    int h = i >> 11, q = i & 2047;
    float base = PI_F * (float)q * (1.0f / 2047.0f);
    ushort_t row[32];
    row[0] = f2bf(coef[h * 6] * LOG2E);
    #pragma unroll
    for (int k = 1; k <= 5; k++) {
      float ck = coef[h * 6 + k] * LOG2E;
      float a = base * (float)k;
      row[2 * k - 1] = f2bf(ck * cosf(a));
      row[2 * k]     = f2bf(ck * sinf(a));
    }
    row[11] = f2bf(1.0f);
    #pragma unroll
    for (int j = 12; j < 32; j++) row[j] = 0;
    ull_t* dst = (ull_t*)(qe + ((size_t)(h * 2048 + q)) * 32);
    #pragma unroll
    for (int j = 0; j < 4; j++) {
      ull_t pk = 0;
      #pragma unroll
      for (int e = 0; e < 4; e++) pk |= (ull_t)row[j * 4 + e] << (16 * e);
      dst[j] = pk;
    }
  }
}

// ---- W'[h*64+d'][:] = sum_d A_h[h][d][d'] * Wq[h*64+d][:]; bq2 = bq.Ah ----
__global__ __launch_bounds__(256) void k_wq(
    const float* __restrict__ Wq, const float* __restrict__ Ah,
    const float* __restrict__ bq, ushort_t* __restrict__ w3, float* __restrict__ bq2) {
  __shared__ float wq_s[64][65];
  __shared__ float ah_s[64][65];
  int h = blockIdx.y, ct = blockIdx.x;
  int t = threadIdx.x;
  #pragma unroll
  for (int i = 0; i < 16; i++) {
    int idx = i * 256 + t, r = idx >> 6, c = idx & 63;
    wq_s[r][c] = Wq[((size_t)h * 64 + r) * 1024 + ct * 64 + c];
    ah_s[r][c] = Ah[((size_t)h * 64 + r) * 64 + c];
  }
  __syncthreads();
  int dp = t >> 2, cg = (t & 3) * 16;
  float acc[16];
  #pragma unroll
  for (int j = 0; j < 16; j++) acc[j] = 0.f;
  for (int d = 0; d < 64; d++) {
    float a = ah_s[d][dp];
    #pragma unroll
    for (int j = 0; j < 16; j++) acc[j] += a * wq_s[d][cg + j];
  }
  ushort_t* orow = w3 + ((size_t)h * 64 + dp) * 1024 + ct * 64 + cg;
  #pragma unroll
  for (int j = 0; j < 16; j += 4) {
    ull_t pk = (ull_t)f2bf(acc[j]) | ((ull_t)f2bf(acc[j + 1]) << 16)
             | ((ull_t)f2bf(acc[j + 2]) << 32) | ((ull_t)f2bf(acc[j + 3]) << 48);
    *(ull_t*)(orow + j) = pk;
  }
  if (ct == 0 && t < 64) {
    float bsum = 0.f;
    for (int d = 0; d < 64; d++) bsum += bq[h * 64 + d] * ah_s[d][t];
    bq2[h * 64 + t] = bsum;
  }
}

// ---- fused GEMM (XCD-swizzled), single-buffer (validated round 12/15) ----
__global__ __launch_bounds__(256) void k_gemm(
    const ushort_t* __restrict__ hb, const ushort_t* __restrict__ w3,
    const float* __restrict__ bq2, const float* __restrict__ bk,
    const float* __restrict__ bv, ushort_t* __restrict__ qk, ushort_t* __restrict__ vT) {
  __shared__ ushort_t Asm[128 * 32];
  __shared__ ushort_t Bsm[128 * 32];
  const int tid = threadIdx.x, w = tid >> 6, l = tid & 63, g = l >> 4, l15 = l & 15;
  const int raw = blockIdx.x;
  const int id = (raw & 7) * 96 + (raw >> 3);  // bijective XCD chunking (768 = 8*96)
  const bool isv = id >= 512;
  int bx, by;
  const ushort_t *Aptr, *Bptr;
  if (!isv) { bx = id & 31; by = id >> 5; Aptr = hb; Bptr = w3; }
  else { int id2 = id - 512; bx = id2 & 7; by = id2 >> 3; Aptr = w3 + 2048 * 1024; Bptr = hb; }
  const int mbase = bx * 128, nbase = by * 128;
  const int wrow = (w >> 1) * 64, wcol = (w & 1) * 64;
  f32x4 zero4 = {0.f, 0.f, 0.f, 0.f};
  f32x4 acc[4][4];
  #pragma unroll
  for (int i = 0; i < 4; i++)
    #pragma unroll
    for (int j = 0; j < 4; j++) acc[i][j] = zero4;

  for (int kt = 0; kt < 32; ++kt) {
    __syncthreads();
    #pragma unroll
    for (int i = 0; i < 2; i++) {
      int inst = w * 2 + i;
      int r = inst * 16 + (l >> 2);
      int cs = (l & 3) ^ (r & 3);
      load_lds16(Aptr + (size_t)(mbase + r) * 1024 + kt * 32 + cs * 8, &Asm[inst * 512]);
      load_lds16(Bptr + (size_t)(nbase + r) * 1024 + kt * 32 + cs * 8, &Bsm[inst * 512]);
    }
    __syncthreads();
    bf16x8 a[4], bfr[4];
    #pragma unroll
    for (int rt = 0; rt < 4; rt++) {
      int r = wrow + rt * 16 + l15;
      a[rt] = *(const bf16x8*)(&Asm[r * 32 + ((g ^ (r & 3)) << 3)]);
    }
    #pragma unroll
    for (int ct = 0; ct < 4; ct++) {
      int r = wcol + ct * 16 + l15;
      bfr[ct] = *(const bf16x8*)(&Bsm[r * 32 + ((g ^ (r & 3)) << 3)]);
    }
    #pragma unroll
    for (int rt = 0; rt < 4; rt++)
      #pragma unroll
      for (int ct = 0; ct < 4; ct++)
        acc[rt][ct] = mfma16(a[rt], bfr[ct], acc[rt][ct]);
  }
  if (!isv) {
    #pragma unroll
    for (int ct = 0; ct < 4; ct++) {
      int n = nbase + wcol + ct * 16 + l15;
      float bias = (n < 1024) ? bq2[n] : bk[n - 1024];
      #pragma unroll
      for (int rt = 0; rt < 4; rt++)
        #pragma unroll
        for (int reg = 0; reg < 4; reg++) {
          int m = mbase + wrow + rt * 16 + g * 4 + reg;
          qk[(size_t)m * 2048 + n] = f2bf(acc[rt][ct][reg] + bias);
        }
    }
  } else {
    #pragma unroll
    for (int rt = 0; rt < 4; rt++)
      #pragma unroll
      for (int reg = 0; reg < 4; reg++) {
        int dg = mbase + wrow + rt * 16 + g * 4 + reg;
        float bias = bv[dg];
        ushort_t* vrow = vT + ((size_t)(dg >> 6)) * 131072 + (size_t)(dg & 63) * 2048;
        #pragma unroll
        for (int ct = 0; ct < 4; ct++) {
          int mg = nbase + wcol + ct * 16 + l15;
          vrow[((size_t)(mg >> 11)) * 2097152 + (mg & 2047)] = f2bf(acc[rt][ct][reg] + bias);
        }
      }
  }
}

// ---- flash attention, K=96: ke columns direct-from-global (register-pipelined) ----
// 4 waves x 16 q = 64 q/block, KVB=64, grid 1024, LDS 32KB -> 5 blocks/CU.
// P in registers; softmax pv = exp2(ST) (logit already has bias+mask, log2 domain).
__global__ __launch_bounds__(256, 5) void k_attn(
    const ushort_t* __restrict__ qk, const ushort_t* __restrict__ vT,
    const ushort_t* __restrict__ qe, const ushort_t* __restrict__ ke,
    float* __restrict__ out) {
  __shared__ ushort_t k_sm[2][64][64];    // 16 KB, phys chunk p holds global chunk p^f(m)
  __shared__ ushort_t vt_sm[2][64][64];   // 16 KB, same swizzle by d
  const int tid = threadIdx.x, w = tid >> 6, l = tid & 63, g = l >> 4, l15 = l & 15;
  const int e01 = l15 & 3, a0 = (l15 >> 2) & 1;
  const int lr = l >> 3, lc = l & 7;
  // 1024 blocks: each XCD owns 4 bh x 32 q-blocks of 64 rows
  const int bid = blockIdx.x, xcd = bid & 7, slot = bid >> 3;
  const int bh = xcd * 4 + (slot & 3), qb = slot >> 2;
  const int b = bh >> 4, h = bh & 15;
  const int wrow = qb * 64 + w * 16;
  const int q = wrow + l15;

  const ushort_t* kbase = qk + 1024 + h * 64;  // + row*2048
  const ushort_t* vT_bh = vT + (size_t)bh * 64 * 2048;
  const ushort_t* ke_b = ke + (size_t)b * 2048 * 32;

  // permuted A-row indices (constant per lane)
  const int mr0 = (l15 >> 2) * 8 + e01;
  const int mr1 = mr0 + 4;
  const int mr2 = mr0 + 32;
  const int mr3 = mr0 + 36;

  auto stage = [&](int t, int bi) {
    int kvb = t * 64;
    #pragma unroll
    for (int ii = 0; ii < 2; ii++) {
      int m = w * 16 + ii * 8 + lr;
      int sc = lc ^ ((lr & 3) | (ii << 2));
      load_lds16(kbase + (size_t)(b * 2048 + kvb + m) * 2048 + sc * 8,
                 &k_sm[bi][w * 16 + ii * 8][0]);
    }
    #pragma unroll
    for (int ii = 0; ii < 2; ii++) {
      int d = w * 16 + ii * 8 + lr;
      int sc = lc ^ ((lr & 3) | (ii << 2));
      load_lds16(vT_bh + (size_t)d * 2048 + kvb + sc * 8,
                 &vt_sm[bi][w * 16 + ii * 8][0]);
    }
  };

  stage(0, 0);

  bf16x8 qf[2], qfe;
  {
    const ushort_t* qpr = qk + (size_t)(b * 2048 + q) * 2048 + h * 64 + g * 8;
    qf[0] = *(const bf16x8*)(qpr);
    qf[1] = *(const bf16x8*)(qpr + 32);
    qfe = *(const bf16x8*)(qe + ((size_t)(h * 2048 + q)) * 32 + g * 8);
  }
  // preload ke fragments for tile 0
  bf16x8 kef0 = *(const bf16x8*)(ke_b + (size_t)mr0 * 32 + g * 8);
  bf16x8 kef1 = *(const bf16x8*)(ke_b + (size_t)mr1 * 32 + g * 8);
  bf16x8 kef2 = *(const bf16x8*)(ke_b + (size_t)mr2 * 32 + g * 8);
  bf16x8 kef3 = *(const bf16x8*)(ke_b + (size_t)mr3 * 32 + g * 8);

  f32x4 zero4 = {0.f, 0.f, 0.f, 0.f};
  f32x4 ctx[4];
  float lrow = 0.f;  // lane-local partial row sum; reduced once after the loop
  #pragma unroll
  for (int dt = 0; dt < 4; dt++) ctx[dt] = zero4;

  __syncthreads();  // drains stage(0)'s global_load_lds + barrier

  for (int t = 0; t < 32; t++) {
    const int bi = t & 1;
    bf16x8 kn0, kn1, kn2, kn3;
    if (t < 31) {
      stage(t + 1, bi ^ 1);  // overlaps compute; drained at iter end
      const ushort_t* kp = ke_b + (size_t)(t + 1) * 64 * 32 + g * 8;
      kn0 = *(const bf16x8*)(kp + (size_t)mr0 * 32);
      kn1 = *(const bf16x8*)(kp + (size_t)mr1 * 32);
      kn2 = *(const bf16x8*)(kp + (size_t)mr2 * 32);
      kn3 = *(const bf16x8*)(kp + (size_t)mr3 * 32);
    }

    // QK^T (swapped + row-permuted): ST[mt][reg] = logit[q][m]
    f32x4 ST[4];
    #pragma unroll
    for (int mt = 0; mt < 4; mt++) ST[mt] = zero4;
    #pragma unroll
    for (int ks = 0; ks < 2; ks++) {
      #pragma unroll
      for (int mt = 0; mt < 4; mt++) {
        int mr = (mt >> 1) * 32 + (l15 >> 2) * 8 + (mt & 1) * 4 + e01;
        int pc = (ks * 4 + g) ^ (e01 | (a0 << 2));
        bf16x8 af = *(const bf16x8*)(&k_sm[bi][mr][pc * 8]);
        ST[mt] = mfma16(af, qf[ks], ST[mt]);
      }
    }
    // ext kstep: bias+mask rank-12 columns (ke frags in registers)
    ST[0] = mfma16(kef0, qfe, ST[0]);
    ST[1] = mfma16(kef1, qfe, ST[1]);
    ST[2] = mfma16(kef2, qfe, ST[2]);
    ST[3] = mfma16(kef3, qfe, ST[3]);

    // softmax: pv = 2^ST (bounded logits, no overflow)
    float pv[4][4];
    #pragma unroll
    for (int mt = 0; mt < 4; mt++) {
      pv[mt][0] = exp2_(ST[mt][0]);
      pv[mt][1] = exp2_(ST[mt][1]);
      pv[mt][2] = exp2_(ST[mt][2]);
      pv[mt][3] = exp2_(ST[mt][3]);
      lrow += pv[mt][0] + pv[mt][1] + pv[mt][2] + pv[mt][3];
    }
    bf16x8 pf[2];
    {
      union { unsigned u[4]; bf16x8 v; } pk0, pk1;
      pk0.u[0] = cvt_pk_bf16(pv[0][0], pv[0][1]);
      pk0.u[1] = cvt_pk_bf16(pv[0][2], pv[0][3]);
      pk0.u[2] = cvt_pk_bf16(pv[1][0], pv[1][1]);
      pk0.u[3] = cvt_pk_bf16(pv[1][2], pv[1][3]);
      pk1.u[0] = cvt_pk_bf16(pv[2][0], pv[2][1]);
      pk1.u[1] = cvt_pk_bf16(pv[2][2], pv[2][3]);
      pk1.u[2] = cvt_pk_bf16(pv[3][0], pv[3][1]);
      pk1.u[3] = cvt_pk_bf16(pv[3][2], pv[3][3]);
      pf[0] = pk0.v;
      pf[1] = pk1.v;
    }

    // PV: ctx[dt] += V^T-frag x P-frag (P in regs)
    #pragma unroll
    for (int kp = 0; kp < 2; kp++) {
      #pragma unroll
      for (int dt = 0; dt < 4; dt++) {
        int d = dt * 16 + l15;
        int pc = (kp * 4 + g) ^ (e01 | (((l15 >> 3) & 1) << 2));
        bf16x8 vf = *(const bf16x8*)(&vt_sm[bi][d][pc * 8]);
        ctx[dt] = mfma16(vf, pf[kp], ctx[dt]);
      }
    }

    kef0 = kn0; kef1 = kn1; kef2 = kn2; kef3 = kn3;
    // drains stage(t+1) and orders this tile's reads before next overwrite of buf bi
    __syncthreads();
  }

  // final row-sum reduction across the 4 g-lanes holding row q
  lrow += __shfl_xor(lrow, 16);
  lrow += __shfl_xor(lrow, 32);
  float inv = 1.0f / lrow;
  float* op = out + ((size_t)(b * 2048 + q)) * 1024 + h * 64 + g * 4;
  #pragma unroll
  for (int dt = 0; dt < 4; dt++) {
    float4 o = {ctx[dt][0] * inv, ctx[dt][1] * inv, ctx[dt][2] * inv, ctx[dt][3] * inv};
    *(float4*)(op + dt * 16) = o;
  }
}

extern "C" void kernel_launch(void* const* d_in, const int* in_sizes, int n_in,
                              void* d_out, int out_size, void* d_ws, size_t ws_size,
                              hipStream_t stream) {
  const float* hidden = (const float*)d_in[0];
  const float* maskp  = (const float*)d_in[1];
  const float* Wq     = (const float*)d_in[2];
  const float* bq     = (const float*)d_in[3];
  const float* Wk     = (const float*)d_in[4];
  const float* bk     = (const float*)d_in[5];
  const float* Wv     = (const float*)d_in[6];
  const float* bv     = (const float*)d_in[7];
  const float* qpw    = (const float*)d_in[8];
  const float* kpw    = (const float*)d_in[9];
  const float* coef   = (const float*)d_in[10];

  char* ws = (char*)d_ws;
  ushort_t* keb   = (ushort_t*)(ws);                  // 2*2048*32*2 = 262,144
  ushort_t* hb    = (ushort_t*)(ws + 262144);         // 8,388,608
  ushort_t* w3    = (ushort_t*)(ws + 8650752);        // 6,291,456 (Q' / K / Wv bf16)
  float*    Ah    = (float*)(ws + 14942208);          // 262,144
  float*    bq2   = (float*)(ws + 15204352);          // 4,096
  ushort_t* qeb   = (ushort_t*)(ws + 15208448);       // 16*2048*32*2 = 2,097,152
  ushort_t* qkb   = (ushort_t*)(ws + 17305600);       // 4096*2048*2 = 16,777,216
  ushort_t* vTb   = (ushort_t*)(ws + 34082816);       // 32*64*2048*2 = 8,388,608 (end 42,471,424)

  k_prep<<<6352, 256, 0, stream>>>(hidden, Wk, Wv, qpw, kpw, coef, maskp,
                                   hb, w3, Ah, keb, qeb);
  k_wq<<<dim3(16, 16), 256, 0, stream>>>(Wq, Ah, bq, w3, bq2);
  k_gemm<<<768, 256, 0, stream>>>(hb, w3, bq2, bk, bv, qkb, vTb);
  k_attn<<<1024, 256, 0, stream>>>(qkb, vTb, qeb, keb, (float*)d_out);
}

// Round 17
// 143.171 us; speedup vs baseline: 1.0466x; 1.0466x over previous
//
#include <hip/hip_runtime.h>

// OrthogonalBasisSelfAttention: B=2, L=2048, D=1024, H=16, DH=64, R=512, NUM_BASIS=6
// scores = q.(Wqp Wkp^T/sqrt(R)).k^T -> fold A_h (x log2e) into Wq'; S = qt.k^T (K=64).
// DCT bias + mask folded as rank-12 columns (qe/ke) into QK^T (K=96); softmax = exp2(ST).
// R17: best-validated assembly — merged k_prep (R16, −8µs), single-buffer k_gemm (R12),
// R15 k_attn (ke staged via LDS, 40KB, 53.6µs measured; R16's direct-global ke regressed).

typedef unsigned short ushort_t;
typedef unsigned long long ull_t;
typedef __attribute__((ext_vector_type(8))) short bf16x8;   // 8 bf16 = 4 VGPR (MFMA A/B frag)
typedef __attribute__((ext_vector_type(4))) float f32x4;    // MFMA C/D frag

#define LOG2E 1.4426950408889634f
#define PI_F 3.14159265358979323846f

__device__ inline f32x4 mfma16(bf16x8 a, bf16x8 b, f32x4 c) {
  return __builtin_amdgcn_mfma_f32_16x16x32_bf16(a, b, c, 0, 0, 0);
}
__device__ inline void load_lds16(const void* g, void* l) {
  __builtin_amdgcn_global_load_lds((const __attribute__((address_space(1))) unsigned int*)g,
                                   (__attribute__((address_space(3))) unsigned int*)l, 16, 0, 0);
}
__device__ inline ushort_t f2bf(float f) {  // round-to-nearest-even
  union { float f; unsigned int u; } v; v.f = f;
  unsigned int u = v.u;
  return (ushort_t)((u + 0x7fffu + ((u >> 16) & 1u)) >> 16);
}
__device__ inline unsigned cvt_pk_bf16(float lo, float hi) {
  unsigned r;
  asm("v_cvt_pk_bf16_f32 %0, %1, %2" : "=v"(r) : "v"(lo), "v"(hi));
  return r;
}
#if __has_builtin(__builtin_amdgcn_exp2f)
__device__ inline float exp2_(float x) { return __builtin_amdgcn_exp2f(x); }
#else
__device__ inline float exp2_(float x) { return exp2f(x); }
#endif

// ---- k_prep: Ah (in-kernel kpw transpose, grid-front) + cvt + ke/qe tables ----
// blocks [0,64): Ah[h][d][d'] = sum_r qpw[h][d][r]*kpw[h][d'][r] * C  (r-chunked LDS transpose)
// blocks [64,6208): fp32->bf16 cvt (hidden / Wk / Wv)
// blocks [6208,6224): ke[b][m][32]; blocks [6224,6352): qe[h][q][32]
__global__ __launch_bounds__(256) void k_prep(
    const float* __restrict__ hidden, const float* __restrict__ Wk,
    const float* __restrict__ Wv, const float* __restrict__ qpw,
    const float* __restrict__ kpw, const float* __restrict__ coef,
    const float* __restrict__ maskp,
    ushort_t* __restrict__ hb, ushort_t* __restrict__ w3, float* __restrict__ Ah,
    ushort_t* __restrict__ ke, ushort_t* __restrict__ qe) {
  __shared__ float tile[64][65];
  const int blk = blockIdx.x, tid = threadIdx.x;
  if (blk < 64) {
    int h = blk >> 2, db = (blk & 3) * 16;
    int dp = tid & 63, d0 = db + (tid >> 6) * 4;
    float acc[4] = {0.f, 0.f, 0.f, 0.f};
    const float* kh = kpw + (size_t)h * 64 * 512;
    const float* qr = qpw + ((size_t)h * 64 + d0) * 512;
    for (int rc = 0; rc < 8; rc++) {
      __syncthreads();
      #pragma unroll
      for (int i = 0; i < 4; i++) {
        int idx = i * 256 + tid;              // 1024 float4 = 64 rows x 64 cols
        int d = idx >> 4, c4 = idx & 15;
        float4 v = *(const float4*)(kh + (size_t)d * 512 + rc * 64 + c4 * 4);
        *(float4*)(&tile[d][c4 * 4]) = v;
      }
      __syncthreads();
      for (int rr = 0; rr < 64; rr += 4) {
        float4 wk = *(const float4*)(&tile[dp][rr]);  // kpw[h][dp][rc*64+rr..+3]
        int r = rc * 64 + rr;
        #pragma unroll
        for (int i = 0; i < 4; i++) {
          float4 wq = *(const float4*)(qr + i * 512 + r);
          acc[i] += wq.x * wk.x + wq.y * wk.y + wq.z * wk.z + wq.w * wk.w;
        }
      }
    }
    #pragma unroll
    for (int i = 0; i < 4; i++)
      Ah[((size_t)h * 64 + d0 + i) * 64 + dp] = acc[i] * (0.044194173824159216f * LOG2E);
  } else if (blk < 6208) {
    const float* in;
    ushort_t* out;
    int base = blk - 64;
    if (base < 4096) { in = hidden; out = hb; }
    else if (base < 5120) { in = Wk; out = w3 + 1048576; base -= 4096; }
    else { in = Wv; out = w3 + 2097152; base -= 5120; }
    int i = (base * 256 + tid) * 4;
    float4 v = *(const float4*)(in + i);
    ull_t pk = (ull_t)f2bf(v.x) | ((ull_t)f2bf(v.y) << 16)
             | ((ull_t)f2bf(v.z) << 32) | ((ull_t)f2bf(v.w) << 48);
    *(ull_t*)(out + i) = pk;
  } else if (blk < 6224) {
    int i = (blk - 6208) * 256 + tid;      // 0..4095
    int bb = i >> 11, m = i & 2047;
    float base = PI_F * (float)m * (1.0f / 2047.0f);
    ushort_t row[32];
    row[0] = f2bf(1.0f);
    #pragma unroll
    for (int k = 1; k <= 5; k++) {
      float a = base * (float)k;
      row[2 * k - 1] = f2bf(cosf(a));
      row[2 * k]     = f2bf(sinf(a));
    }
    row[11] = f2bf(maskp[bb * 2048 + m] * LOG2E);
    #pragma unroll
    for (int j = 12; j < 32; j++) row[j] = 0;
    ull_t* dst = (ull_t*)(ke + ((size_t)(bb * 2048 + m)) * 32);
    #pragma unroll
    for (int j = 0; j < 4; j++) {
      ull_t pk = 0;
      #pragma unroll
      for (int e = 0; e < 4; e++) pk |= (ull_t)row[j * 4 + e] << (16 * e);
      dst[j] = pk;
    }
  } else {
    int i = (blk - 6224) * 256 + tid;      // 0..32767
    int h = i >> 11, q = i & 2047;
    float base = PI_F * (float)q * (1.0f / 2047.0f);
    ushort_t row[32];
    row[0] = f2bf(coef[h * 6] * LOG2E);
    #pragma unroll
    for (int k = 1; k <= 5; k++) {
      float ck = coef[h * 6 + k] * LOG2E;
      float a = base * (float)k;
      row[2 * k - 1] = f2bf(ck * cosf(a));
      row[2 * k]     = f2bf(ck * sinf(a));
    }
    row[11] = f2bf(1.0f);
    #pragma unroll
    for (int j = 12; j < 32; j++) row[j] = 0;
    ull_t* dst = (ull_t*)(qe + ((size_t)(h * 2048 + q)) * 32);
    #pragma unroll
    for (int j = 0; j < 4; j++) {
      ull_t pk = 0;
      #pragma unroll
      for (int e = 0; e < 4; e++) pk |= (ull_t)row[j * 4 + e] << (16 * e);
      dst[j] = pk;
    }
  }
}

// ---- W'[h*64+d'][:] = sum_d A_h[h][d][d'] * Wq[h*64+d][:]; bq2 = bq.Ah ----
__global__ __launch_bounds__(256) void k_wq(
    const float* __restrict__ Wq, const float* __restrict__ Ah,
    const float* __restrict__ bq, ushort_t* __restrict__ w3, float* __restrict__ bq2) {
  __shared__ float wq_s[64][65];
  __shared__ float ah_s[64][65];
  int h = blockIdx.y, ct = blockIdx.x;
  int t = threadIdx.x;
  #pragma unroll
  for (int i = 0; i < 16; i++) {
    int idx = i * 256 + t, r = idx >> 6, c = idx & 63;
    wq_s[r][c] = Wq[((size_t)h * 64 + r) * 1024 + ct * 64 + c];
    ah_s[r][c] = Ah[((size_t)h * 64 + r) * 64 + c];
  }
  __syncthreads();
  int dp = t >> 2, cg = (t & 3) * 16;
  float acc[16];
  #pragma unroll
  for (int j = 0; j < 16; j++) acc[j] = 0.f;
  for (int d = 0; d < 64; d++) {
    float a = ah_s[d][dp];
    #pragma unroll
    for (int j = 0; j < 16; j++) acc[j] += a * wq_s[d][cg + j];
  }
  ushort_t* orow = w3 + ((size_t)h * 64 + dp) * 1024 + ct * 64 + cg;
  #pragma unroll
  for (int j = 0; j < 16; j += 4) {
    ull_t pk = (ull_t)f2bf(acc[j]) | ((ull_t)f2bf(acc[j + 1]) << 16)
             | ((ull_t)f2bf(acc[j + 2]) << 32) | ((ull_t)f2bf(acc[j + 3]) << 48);
    *(ull_t*)(orow + j) = pk;
  }
  if (ct == 0 && t < 64) {
    float bsum = 0.f;
    for (int d = 0; d < 64; d++) bsum += bq[h * 64 + d] * ah_s[d][t];
    bq2[h * 64 + t] = bsum;
  }
}

// ---- fused GEMM (XCD-swizzled), single-buffer (validated rounds 12/15/16) ----
__global__ __launch_bounds__(256) void k_gemm(
    const ushort_t* __restrict__ hb, const ushort_t* __restrict__ w3,
    const float* __restrict__ bq2, const float* __restrict__ bk,
    const float* __restrict__ bv, ushort_t* __restrict__ qk, ushort_t* __restrict__ vT) {
  __shared__ ushort_t Asm[128 * 32];
  __shared__ ushort_t Bsm[128 * 32];
  const int tid = threadIdx.x, w = tid >> 6, l = tid & 63, g = l >> 4, l15 = l & 15;
  const int raw = blockIdx.x;
  const int id = (raw & 7) * 96 + (raw >> 3);  // bijective XCD chunking (768 = 8*96)
  const bool isv = id >= 512;
  int bx, by;
  const ushort_t *Aptr, *Bptr;
  if (!isv) { bx = id & 31; by = id >> 5; Aptr = hb; Bptr = w3; }
  else { int id2 = id - 512; bx = id2 & 7; by = id2 >> 3; Aptr = w3 + 2048 * 1024; Bptr = hb; }
  const int mbase = bx * 128, nbase = by * 128;
  const int wrow = (w >> 1) * 64, wcol = (w & 1) * 64;
  f32x4 zero4 = {0.f, 0.f, 0.f, 0.f};
  f32x4 acc[4][4];
  #pragma unroll
  for (int i = 0; i < 4; i++)
    #pragma unroll
    for (int j = 0; j < 4; j++) acc[i][j] = zero4;

  for (int kt = 0; kt < 32; ++kt) {
    __syncthreads();
    #pragma unroll
    for (int i = 0; i < 2; i++) {
      int inst = w * 2 + i;
      int r = inst * 16 + (l >> 2);
      int cs = (l & 3) ^ (r & 3);
      load_lds16(Aptr + (size_t)(mbase + r) * 1024 + kt * 32 + cs * 8, &Asm[inst * 512]);
      load_lds16(Bptr + (size_t)(nbase + r) * 1024 + kt * 32 + cs * 8, &Bsm[inst * 512]);
    }
    __syncthreads();
    bf16x8 a[4], bfr[4];
    #pragma unroll
    for (int rt = 0; rt < 4; rt++) {
      int r = wrow + rt * 16 + l15;
      a[rt] = *(const bf16x8*)(&Asm[r * 32 + ((g ^ (r & 3)) << 3)]);
    }
    #pragma unroll
    for (int ct = 0; ct < 4; ct++) {
      int r = wcol + ct * 16 + l15;
      bfr[ct] = *(const bf16x8*)(&Bsm[r * 32 + ((g ^ (r & 3)) << 3)]);
    }
    #pragma unroll
    for (int rt = 0; rt < 4; rt++)
      #pragma unroll
      for (int ct = 0; ct < 4; ct++)
        acc[rt][ct] = mfma16(a[rt], bfr[ct], acc[rt][ct]);
  }
  if (!isv) {
    #pragma unroll
    for (int ct = 0; ct < 4; ct++) {
      int n = nbase + wcol + ct * 16 + l15;
      float bias = (n < 1024) ? bq2[n] : bk[n - 1024];
      #pragma unroll
      for (int rt = 0; rt < 4; rt++)
        #pragma unroll
        for (int reg = 0; reg < 4; reg++) {
          int m = mbase + wrow + rt * 16 + g * 4 + reg;
          qk[(size_t)m * 2048 + n] = f2bf(acc[rt][ct][reg] + bias);
        }
    }
  } else {
    #pragma unroll
    for (int rt = 0; rt < 4; rt++)
      #pragma unroll
      for (int reg = 0; reg < 4; reg++) {
        int dg = mbase + wrow + rt * 16 + g * 4 + reg;
        float bias = bv[dg];
        ushort_t* vrow = vT + ((size_t)(dg >> 6)) * 131072 + (size_t)(dg & 63) * 2048;
        #pragma unroll
        for (int ct = 0; ct < 4; ct++) {
          int mg = nbase + wcol + ct * 16 + l15;
          vrow[((size_t)(mg >> 11)) * 2097152 + (mg & 2047)] = f2bf(acc[rt][ct][reg] + bias);
        }
      }
  }
}

// ---- flash attention, K=96 (64 qt.k + 32 rank-12 bias/mask columns), R15 version ----
// 4 waves x 16 q = 64 q/block, KVB=64, grid 1024, 4 blk/CU, LDS 40KB.
// P in registers; softmax pv = exp2(ST) (logit already has bias+mask, log2 domain).
__global__ __launch_bounds__(256, 4) void k_attn(
    const ushort_t* __restrict__ qk, const ushort_t* __restrict__ vT,
    const ushort_t* __restrict__ qe, const ushort_t* __restrict__ ke,
    float* __restrict__ out) {
  __shared__ ushort_t k_sm[2][64][64];    // 16 KB, phys chunk p holds global chunk p^f(m)
  __shared__ ushort_t vt_sm[2][64][64];   // 16 KB, same swizzle by d
  __shared__ ushort_t ke_sm[2][64][32];   // 8 KB, phys chunk c holds global chunk c^(m&3)
  const int tid = threadIdx.x, w = tid >> 6, l = tid & 63, g = l >> 4, l15 = l & 15;
  const int e01 = l15 & 3, a0 = (l15 >> 2) & 1;
  const int lr = l >> 3, lc = l & 7;
  // 1024 blocks: each XCD owns 4 bh x 32 q-blocks of 64 rows
  const int bid = blockIdx.x, xcd = bid & 7, slot = bid >> 3;
  const int bh = xcd * 4 + (slot & 3), qb = slot >> 2;
  const int b = bh >> 4, h = bh & 15;
  const int wrow = qb * 64 + w * 16;
  const int q = wrow + l15;

  const ushort_t* kbase = qk + 1024 + h * 64;  // + row*2048
  const ushort_t* vT_bh = vT + (size_t)bh * 64 * 2048;
  const ushort_t* ke_b = ke + (size_t)b * 2048 * 32;

  auto stage = [&](int t, int bi) {
    int kvb = t * 64;
    #pragma unroll
    for (int ii = 0; ii < 2; ii++) {
      int m = w * 16 + ii * 8 + lr;
      int sc = lc ^ ((lr & 3) | (ii << 2));
      load_lds16(kbase + (size_t)(b * 2048 + kvb + m) * 2048 + sc * 8,
                 &k_sm[bi][w * 16 + ii * 8][0]);
    }
    #pragma unroll
    for (int ii = 0; ii < 2; ii++) {
      int d = w * 16 + ii * 8 + lr;
      int sc = lc ^ ((lr & 3) | (ii << 2));
      load_lds16(vT_bh + (size_t)d * 2048 + kvb + sc * 8,
                 &vt_sm[bi][w * 16 + ii * 8][0]);
    }
    {  // ke rows: wave w stages rows w*16..w*16+15 (64B each), 1 load16/lane
      int ml = l >> 2, c = l & 3;
      load_lds16(ke_b + (size_t)(kvb + w * 16 + ml) * 32 + ((c ^ (ml & 3)) << 3),
                 &ke_sm[bi][w * 16][0]);
    }
  };

  stage(0, 0);

  bf16x8 qf[2], qfe;
  {
    const ushort_t* qpr = qk + (size_t)(b * 2048 + q) * 2048 + h * 64 + g * 8;
    qf[0] = *(const bf16x8*)(qpr);
    qf[1] = *(const bf16x8*)(qpr + 32);
    qfe = *(const bf16x8*)(qe + ((size_t)(h * 2048 + q)) * 32 + g * 8);
  }

  f32x4 zero4 = {0.f, 0.f, 0.f, 0.f};
  f32x4 ctx[4];
  float lrow = 0.f;  // lane-local partial row sum; reduced once after the loop
  #pragma unroll
  for (int dt = 0; dt < 4; dt++) ctx[dt] = zero4;

  __syncthreads();  // drains stage(0)'s global_load_lds + barrier

  for (int t = 0; t < 32; t++) {
    const int bi = t & 1;
    if (t < 31) stage(t + 1, bi ^ 1);  // overlaps compute; drained at iter end

    // QK^T (swapped + row-permuted): ST[mt][reg] = logit[q][m=kvb+(mt>>1)*32+g*8+(mt&1)*4+reg]
    f32x4 ST[4];
    #pragma unroll
    for (int mt = 0; mt < 4; mt++) ST[mt] = zero4;
    #pragma unroll
    for (int ks = 0; ks < 2; ks++) {
      #pragma unroll
      for (int mt = 0; mt < 4; mt++) {
        int mr = (mt >> 1) * 32 + (l15 >> 2) * 8 + (mt & 1) * 4 + e01;  // permuted A-row
        int pc = (ks * 4 + g) ^ (e01 | (a0 << 2));
        bf16x8 af = *(const bf16x8*)(&k_sm[bi][mr][pc * 8]);
        ST[mt] = mfma16(af, qf[ks], ST[mt]);
      }
    }
    #pragma unroll
    for (int mt = 0; mt < 4; mt++) {  // ext kstep: bias+mask rank-12 columns
      int mr = (mt >> 1) * 32 + (l15 >> 2) * 8 + (mt & 1) * 4 + e01;
      bf16x8 af = *(const bf16x8*)(&ke_sm[bi][mr][(g ^ e01) * 8]);
      ST[mt] = mfma16(af, qfe, ST[mt]);
    }

    // softmax: pv = 2^ST (logit already includes bias+mask, log2 domain, bounded)
    float pv[4][4];
    #pragma unroll
    for (int mt = 0; mt < 4; mt++) {
      pv[mt][0] = exp2_(ST[mt][0]);
      pv[mt][1] = exp2_(ST[mt][1]);
      pv[mt][2] = exp2_(ST[mt][2]);
      pv[mt][3] = exp2_(ST[mt][3]);
      lrow += pv[mt][0] + pv[mt][1] + pv[mt][2] + pv[mt][3];
    }
    bf16x8 pf[2];
    {
      union { unsigned u[4]; bf16x8 v; } pk0, pk1;
      pk0.u[0] = cvt_pk_bf16(pv[0][0], pv[0][1]);
      pk0.u[1] = cvt_pk_bf16(pv[0][2], pv[0][3]);
      pk0.u[2] = cvt_pk_bf16(pv[1][0], pv[1][1]);
      pk0.u[3] = cvt_pk_bf16(pv[1][2], pv[1][3]);
      pk1.u[0] = cvt_pk_bf16(pv[2][0], pv[2][1]);
      pk1.u[1] = cvt_pk_bf16(pv[2][2], pv[2][3]);
      pk1.u[2] = cvt_pk_bf16(pv[3][0], pv[3][1]);
      pk1.u[3] = cvt_pk_bf16(pv[3][2], pv[3][3]);
      pf[0] = pk0.v;
      pf[1] = pk1.v;
    }

    // PV: ctx[dt] += V^T-frag x P-frag (P in regs)
    #pragma unroll
    for (int kp = 0; kp < 2; kp++) {
      #pragma unroll
      for (int dt = 0; dt < 4; dt++) {
        int d = dt * 16 + l15;
        int pc = (kp * 4 + g) ^ (e01 | (((l15 >> 3) & 1) << 2));
        bf16x8 vf = *(const bf16x8*)(&vt_sm[bi][d][pc * 8]);
        ctx[dt] = mfma16(vf, pf[kp], ctx[dt]);
      }
    }

    // drains stage(t+1) and orders this tile's reads before next overwrite of buf bi
    __syncthreads();
  }

  // final row-sum reduction across the 4 g-lanes holding row q
  lrow += __shfl_xor(lrow, 16);
  lrow += __shfl_xor(lrow, 32);
  float inv = 1.0f / lrow;
  float* op = out + ((size_t)(b * 2048 + q)) * 1024 + h * 64 + g * 4;
  #pragma unroll
  for (int dt = 0; dt < 4; dt++) {
    float4 o = {ctx[dt][0] * inv, ctx[dt][1] * inv, ctx[dt][2] * inv, ctx[dt][3] * inv};
    *(float4*)(op + dt * 16) = o;
  }
}

extern "C" void kernel_launch(void* const* d_in, const int* in_sizes, int n_in,
                              void* d_out, int out_size, void* d_ws, size_t ws_size,
                              hipStream_t stream) {
  const float* hidden = (const float*)d_in[0];
  const float* maskp  = (const float*)d_in[1];
  const float* Wq     = (const float*)d_in[2];
  const float* bq     = (const float*)d_in[3];
  const float* Wk     = (const float*)d_in[4];
  const float* bk     = (const float*)d_in[5];
  const float* Wv     = (const float*)d_in[6];
  const float* bv     = (const float*)d_in[7];
  const float* qpw    = (const float*)d_in[8];
  const float* kpw    = (const float*)d_in[9];
  const float* coef   = (const float*)d_in[10];

  char* ws = (char*)d_ws;
  ushort_t* keb   = (ushort_t*)(ws);                  // 2*2048*32*2 = 262,144
  ushort_t* hb    = (ushort_t*)(ws + 262144);         // 8,388,608
  ushort_t* w3    = (ushort_t*)(ws + 8650752);        // 6,291,456 (Q' / K / Wv bf16)
  float*    Ah    = (float*)(ws + 14942208);          // 262,144
  float*    bq2   = (float*)(ws + 15204352);          // 4,096
  ushort_t* qeb   = (ushort_t*)(ws + 15208448);       // 16*2048*32*2 = 2,097,152
  ushort_t* qkb   = (ushort_t*)(ws + 17305600);       // 4096*2048*2 = 16,777,216
  ushort_t* vTb   = (ushort_t*)(ws + 34082816);       // 32*64*2048*2 = 8,388,608 (end 42,471,424)

  k_prep<<<6352, 256, 0, stream>>>(hidden, Wk, Wv, qpw, kpw, coef, maskp,
                                   hb, w3, Ah, keb, qeb);
  k_wq<<<dim3(16, 16), 256, 0, stream>>>(Wq, Ah, bq, w3, bq2);
  k_gemm<<<768, 256, 0, stream>>>(hb, w3, bq2, bk, bv, qkb, vTb);
  k_attn<<<1024, 256, 0, stream>>>(qkb, vTb, qeb, keb, (float*)d_out);
}

// Round 18
// 139.472 us; speedup vs baseline: 1.0744x; 1.0265x over previous
//
#include <hip/hip_runtime.h>

// OrthogonalBasisSelfAttention: B=2, L=2048, D=1024, H=16, DH=64, R=512, NUM_BASIS=6
// scores = q.(Wqp Wkp^T/sqrt(R)).k^T -> fold A_h (x log2e) into Wq'; S = qt.k^T (K=64).
// DCT bias + mask folded as rank-12 columns (qe/ke) into QK^T (K=96); softmax = exp2(ST).
// R18: k_gemm BK=64 (32 MFMA per barrier pair, LDS 32KB) — bit-identical accumulation
// order vs BK=32. k_prep (merged, R16), k_wq, R15 k_attn unchanged.

typedef unsigned short ushort_t;
typedef unsigned long long ull_t;
typedef __attribute__((ext_vector_type(8))) short bf16x8;   // 8 bf16 = 4 VGPR (MFMA A/B frag)
typedef __attribute__((ext_vector_type(4))) float f32x4;    // MFMA C/D frag

#define LOG2E 1.4426950408889634f
#define PI_F 3.14159265358979323846f

__device__ inline f32x4 mfma16(bf16x8 a, bf16x8 b, f32x4 c) {
  return __builtin_amdgcn_mfma_f32_16x16x32_bf16(a, b, c, 0, 0, 0);
}
__device__ inline void load_lds16(const void* g, void* l) {
  __builtin_amdgcn_global_load_lds((const __attribute__((address_space(1))) unsigned int*)g,
                                   (__attribute__((address_space(3))) unsigned int*)l, 16, 0, 0);
}
__device__ inline ushort_t f2bf(float f) {  // round-to-nearest-even
  union { float f; unsigned int u; } v; v.f = f;
  unsigned int u = v.u;
  return (ushort_t)((u + 0x7fffu + ((u >> 16) & 1u)) >> 16);
}
__device__ inline unsigned cvt_pk_bf16(float lo, float hi) {
  unsigned r;
  asm("v_cvt_pk_bf16_f32 %0, %1, %2" : "=v"(r) : "v"(lo), "v"(hi));
  return r;
}
#if __has_builtin(__builtin_amdgcn_exp2f)
__device__ inline float exp2_(float x) { return __builtin_amdgcn_exp2f(x); }
#else
__device__ inline float exp2_(float x) { return exp2f(x); }
#endif

// ---- k_prep: Ah (in-kernel kpw transpose, grid-front) + cvt + ke/qe tables ----
// blocks [0,64): Ah[h][d][d'] = sum_r qpw[h][d][r]*kpw[h][d'][r] * C  (r-chunked LDS transpose)
// blocks [64,6208): fp32->bf16 cvt (hidden / Wk / Wv)
// blocks [6208,6224): ke[b][m][32]; blocks [6224,6352): qe[h][q][32]
__global__ __launch_bounds__(256) void k_prep(
    const float* __restrict__ hidden, const float* __restrict__ Wk,
    const float* __restrict__ Wv, const float* __restrict__ qpw,
    const float* __restrict__ kpw, const float* __restrict__ coef,
    const float* __restrict__ maskp,
    ushort_t* __restrict__ hb, ushort_t* __restrict__ w3, float* __restrict__ Ah,
    ushort_t* __restrict__ ke, ushort_t* __restrict__ qe) {
  __shared__ float tile[64][65];
  const int blk = blockIdx.x, tid = threadIdx.x;
  if (blk < 64) {
    int h = blk >> 2, db = (blk & 3) * 16;
    int dp = tid & 63, d0 = db + (tid >> 6) * 4;
    float acc[4] = {0.f, 0.f, 0.f, 0.f};
    const float* kh = kpw + (size_t)h * 64 * 512;
    const float* qr = qpw + ((size_t)h * 64 + d0) * 512;
    for (int rc = 0; rc < 8; rc++) {
      __syncthreads();
      #pragma unroll
      for (int i = 0; i < 4; i++) {
        int idx = i * 256 + tid;              // 1024 float4 = 64 rows x 64 cols
        int d = idx >> 4, c4 = idx & 15;
        float4 v = *(const float4*)(kh + (size_t)d * 512 + rc * 64 + c4 * 4);
        *(float4*)(&tile[d][c4 * 4]) = v;
      }
      __syncthreads();
      for (int rr = 0; rr < 64; rr += 4) {
        float4 wk = *(const float4*)(&tile[dp][rr]);  // kpw[h][dp][rc*64+rr..+3]
        int r = rc * 64 + rr;
        #pragma unroll
        for (int i = 0; i < 4; i++) {
          float4 wq = *(const float4*)(qr + i * 512 + r);
          acc[i] += wq.x * wk.x + wq.y * wk.y + wq.z * wk.z + wq.w * wk.w;
        }
      }
    }
    #pragma unroll
    for (int i = 0; i < 4; i++)
      Ah[((size_t)h * 64 + d0 + i) * 64 + dp] = acc[i] * (0.044194173824159216f * LOG2E);
  } else if (blk < 6208) {
    const float* in;
    ushort_t* out;
    int base = blk - 64;
    if (base < 4096) { in = hidden; out = hb; }
    else if (base < 5120) { in = Wk; out = w3 + 1048576; base -= 4096; }
    else { in = Wv; out = w3 + 2097152; base -= 5120; }
    int i = (base * 256 + tid) * 4;
    float4 v = *(const float4*)(in + i);
    ull_t pk = (ull_t)f2bf(v.x) | ((ull_t)f2bf(v.y) << 16)
             | ((ull_t)f2bf(v.z) << 32) | ((ull_t)f2bf(v.w) << 48);
    *(ull_t*)(out + i) = pk;
  } else if (blk < 6224) {
    int i = (blk - 6208) * 256 + tid;      // 0..4095
    int bb = i >> 11, m = i & 2047;
    float base = PI_F * (float)m * (1.0f / 2047.0f);
    ushort_t row[32];
    row[0] = f2bf(1.0f);
    #pragma unroll
    for (int k = 1; k <= 5; k++) {
      float a = base * (float)k;
      row[2 * k - 1] = f2bf(cosf(a));
      row[2 * k]     = f2bf(sinf(a));
    }
    row[11] = f2bf(maskp[bb * 2048 + m] * LOG2E);
    #pragma unroll
    for (int j = 12; j < 32; j++) row[j] = 0;
    ull_t* dst = (ull_t*)(ke + ((size_t)(bb * 2048 + m)) * 32);
    #pragma unroll
    for (int j = 0; j < 4; j++) {
      ull_t pk = 0;
      #pragma unroll
      for (int e = 0; e < 4; e++) pk |= (ull_t)row[j * 4 + e] << (16 * e);
      dst[j] = pk;
    }
  } else {
    int i = (blk - 6224) * 256 + tid;      // 0..32767
    int h = i >> 11, q = i & 2047;
    float base = PI_F * (float)q * (1.0f / 2047.0f);
    ushort_t row[32];
    row[0] = f2bf(coef[h * 6] * LOG2E);
    #pragma unroll
    for (int k = 1; k <= 5; k++) {
      float ck = coef[h * 6 + k] * LOG2E;
      float a = base * (float)k;
      row[2 * k - 1] = f2bf(ck * cosf(a));
      row[2 * k]     = f2bf(ck * sinf(a));
    }
    row[11] = f2bf(1.0f);
    #pragma unroll
    for (int j = 12; j < 32; j++) row[j] = 0;
    ull_t* dst = (ull_t*)(qe + ((size_t)(h * 2048 + q)) * 32);
    #pragma unroll
    for (int j = 0; j < 4; j++) {
      ull_t pk = 0;
      #pragma unroll
      for (int e = 0; e < 4; e++) pk |= (ull_t)row[j * 4 + e] << (16 * e);
      dst[j] = pk;
    }
  }
}

// ---- W'[h*64+d'][:] = sum_d A_h[h][d][d'] * Wq[h*64+d][:]; bq2 = bq.Ah ----
__global__ __launch_bounds__(256) void k_wq(
    const float* __restrict__ Wq, const float* __restrict__ Ah,
    const float* __restrict__ bq, ushort_t* __restrict__ w3, float* __restrict__ bq2) {
  __shared__ float wq_s[64][65];
  __shared__ float ah_s[64][65];
  int h = blockIdx.y, ct = blockIdx.x;
  int t = threadIdx.x;
  #pragma unroll
  for (int i = 0; i < 16; i++) {
    int idx = i * 256 + t, r = idx >> 6, c = idx & 63;
    wq_s[r][c] = Wq[((size_t)h * 64 + r) * 1024 + ct * 64 + c];
    ah_s[r][c] = Ah[((size_t)h * 64 + r) * 64 + c];
  }
  __syncthreads();
  int dp = t >> 2, cg = (t & 3) * 16;
  float acc[16];
  #pragma unroll
  for (int j = 0; j < 16; j++) acc[j] = 0.f;
  for (int d = 0; d < 64; d++) {
    float a = ah_s[d][dp];
    #pragma unroll
    for (int j = 0; j < 16; j++) acc[j] += a * wq_s[d][cg + j];
  }
  ushort_t* orow = w3 + ((size_t)h * 64 + dp) * 1024 + ct * 64 + cg;
  #pragma unroll
  for (int j = 0; j < 16; j += 4) {
    ull_t pk = (ull_t)f2bf(acc[j]) | ((ull_t)f2bf(acc[j + 1]) << 16)
             | ((ull_t)f2bf(acc[j + 2]) << 32) | ((ull_t)f2bf(acc[j + 3]) << 48);
    *(ull_t*)(orow + j) = pk;
  }
  if (ct == 0 && t < 64) {
    float bsum = 0.f;
    for (int d = 0; d < 64; d++) bsum += bq[h * 64 + d] * ah_s[d][t];
    bq2[h * 64 + t] = bsum;
  }
}

// ---- fused GEMM (XCD-swizzled), BK=64: 32 MFMA per barrier pair ----
// ids 0..511:   qk[m=4096][n=2048] = hb @ w3[0:2048]^T + {bq2,bk}
// ids 512..767: vT[dg=1024][mg=4096] = Wv @ hb^T + bv, written per-head transposed
// Staging: 128x64 tiles (16 KB each), row = 8 chunks of 16B, phys chunk p holds
// global chunk p^(r&7); fragment read phys = (ks*4+g)^(r&7) -> 2 lanes/chunk (free).
__global__ __launch_bounds__(256) void k_gemm(
    const ushort_t* __restrict__ hb, const ushort_t* __restrict__ w3,
    const float* __restrict__ bq2, const float* __restrict__ bk,
    const float* __restrict__ bv, ushort_t* __restrict__ qk, ushort_t* __restrict__ vT) {
  __shared__ ushort_t Asm[128 * 64];   // 16 KB
  __shared__ ushort_t Bsm[128 * 64];   // 16 KB
  const int tid = threadIdx.x, w = tid >> 6, l = tid & 63, g = l >> 4, l15 = l & 15;
  const int raw = blockIdx.x;
  const int id = (raw & 7) * 96 + (raw >> 3);  // bijective XCD chunking (768 = 8*96)
  const bool isv = id >= 512;
  int bx, by;
  const ushort_t *Aptr, *Bptr;
  if (!isv) { bx = id & 31; by = id >> 5; Aptr = hb; Bptr = w3; }
  else { int id2 = id - 512; bx = id2 & 7; by = id2 >> 3; Aptr = w3 + 2048 * 1024; Bptr = hb; }
  const int mbase = bx * 128, nbase = by * 128;
  const int wrow = (w >> 1) * 64, wcol = (w & 1) * 64;
  f32x4 zero4 = {0.f, 0.f, 0.f, 0.f};
  f32x4 acc[4][4];
  #pragma unroll
  for (int i = 0; i < 4; i++)
    #pragma unroll
    for (int j = 0; j < 4; j++) acc[i][j] = zero4;

  for (int kt = 0; kt < 16; ++kt) {
    __syncthreads();
    #pragma unroll
    for (int i = 0; i < 4; i++) {
      int r0 = i * 32 + w * 8;          // wave writes rows r0..r0+7 (one 1KB slab)
      int r = r0 + (l >> 3);
      int cs = (l & 7) ^ (r & 7);       // pre-swizzled source chunk
      load_lds16(Aptr + (size_t)(mbase + r) * 1024 + kt * 64 + cs * 8, &Asm[r0 * 64]);
      load_lds16(Bptr + (size_t)(nbase + r) * 1024 + kt * 64 + cs * 8, &Bsm[r0 * 64]);
    }
    __syncthreads();
    #pragma unroll
    for (int ks = 0; ks < 2; ks++) {
      bf16x8 a[4], bfr[4];
      #pragma unroll
      for (int rt = 0; rt < 4; rt++) {
        int r = wrow + rt * 16 + l15;
        a[rt] = *(const bf16x8*)(&Asm[r * 64 + (((ks * 4 + g) ^ (r & 7)) << 3)]);
      }
      #pragma unroll
      for (int ct = 0; ct < 4; ct++) {
        int r = wcol + ct * 16 + l15;
        bfr[ct] = *(const bf16x8*)(&Bsm[r * 64 + (((ks * 4 + g) ^ (r & 7)) << 3)]);
      }
      #pragma unroll
      for (int rt = 0; rt < 4; rt++)
        #pragma unroll
        for (int ct = 0; ct < 4; ct++)
          acc[rt][ct] = mfma16(a[rt], bfr[ct], acc[rt][ct]);
    }
  }
  if (!isv) {
    #pragma unroll
    for (int ct = 0; ct < 4; ct++) {
      int n = nbase + wcol + ct * 16 + l15;
      float bias = (n < 1024) ? bq2[n] : bk[n - 1024];
      #pragma unroll
      for (int rt = 0; rt < 4; rt++)
        #pragma unroll
        for (int reg = 0; reg < 4; reg++) {
          int m = mbase + wrow + rt * 16 + g * 4 + reg;
          qk[(size_t)m * 2048 + n] = f2bf(acc[rt][ct][reg] + bias);
        }
    }
  } else {
    #pragma unroll
    for (int rt = 0; rt < 4; rt++)
      #pragma unroll
      for (int reg = 0; reg < 4; reg++) {
        int dg = mbase + wrow + rt * 16 + g * 4 + reg;
        float bias = bv[dg];
        ushort_t* vrow = vT + ((size_t)(dg >> 6)) * 131072 + (size_t)(dg & 63) * 2048;
        #pragma unroll
        for (int ct = 0; ct < 4; ct++) {
          int mg = nbase + wcol + ct * 16 + l15;
          vrow[((size_t)(mg >> 11)) * 2097152 + (mg & 2047)] = f2bf(acc[rt][ct][reg] + bias);
        }
      }
  }
}

// ---- flash attention, K=96 (64 qt.k + 32 rank-12 bias/mask columns), R15 version ----
// 4 waves x 16 q = 64 q/block, KVB=64, grid 1024, 4 blk/CU, LDS 40KB.
// P in registers; softmax pv = exp2(ST) (logit already has bias+mask, log2 domain).
__global__ __launch_bounds__(256, 4) void k_attn(
    const ushort_t* __restrict__ qk, const ushort_t* __restrict__ vT,
    const ushort_t* __restrict__ qe, const ushort_t* __restrict__ ke,
    float* __restrict__ out) {
  __shared__ ushort_t k_sm[2][64][64];    // 16 KB, phys chunk p holds global chunk p^f(m)
  __shared__ ushort_t vt_sm[2][64][64];   // 16 KB, same swizzle by d
  __shared__ ushort_t ke_sm[2][64][32];   // 8 KB, phys chunk c holds global chunk c^(m&3)
  const int tid = threadIdx.x, w = tid >> 6, l = tid & 63, g = l >> 4, l15 = l & 15;
  const int e01 = l15 & 3, a0 = (l15 >> 2) & 1;
  const int lr = l >> 3, lc = l & 7;
  // 1024 blocks: each XCD owns 4 bh x 32 q-blocks of 64 rows
  const int bid = blockIdx.x, xcd = bid & 7, slot = bid >> 3;
  const int bh = xcd * 4 + (slot & 3), qb = slot >> 2;
  const int b = bh >> 4, h = bh & 15;
  const int wrow = qb * 64 + w * 16;
  const int q = wrow + l15;

  const ushort_t* kbase = qk + 1024 + h * 64;  // + row*2048
  const ushort_t* vT_bh = vT + (size_t)bh * 64 * 2048;
  const ushort_t* ke_b = ke + (size_t)b * 2048 * 32;

  auto stage = [&](int t, int bi) {
    int kvb = t * 64;
    #pragma unroll
    for (int ii = 0; ii < 2; ii++) {
      int m = w * 16 + ii * 8 + lr;
      int sc = lc ^ ((lr & 3) | (ii << 2));
      load_lds16(kbase + (size_t)(b * 2048 + kvb + m) * 2048 + sc * 8,
                 &k_sm[bi][w * 16 + ii * 8][0]);
    }
    #pragma unroll
    for (int ii = 0; ii < 2; ii++) {
      int d = w * 16 + ii * 8 + lr;
      int sc = lc ^ ((lr & 3) | (ii << 2));
      load_lds16(vT_bh + (size_t)d * 2048 + kvb + sc * 8,
                 &vt_sm[bi][w * 16 + ii * 8][0]);
    }
    {  // ke rows: wave w stages rows w*16..w*16+15 (64B each), 1 load16/lane
      int ml = l >> 2, c = l & 3;
      load_lds16(ke_b + (size_t)(kvb + w * 16 + ml) * 32 + ((c ^ (ml & 3)) << 3),
                 &ke_sm[bi][w * 16][0]);
    }
  };

  stage(0, 0);

  bf16x8 qf[2], qfe;
  {
    const ushort_t* qpr = qk + (size_t)(b * 2048 + q) * 2048 + h * 64 + g * 8;
    qf[0] = *(const bf16x8*)(qpr);
    qf[1] = *(const bf16x8*)(qpr + 32);
    qfe = *(const bf16x8*)(qe + ((size_t)(h * 2048 + q)) * 32 + g * 8);
  }

  f32x4 zero4 = {0.f, 0.f, 0.f, 0.f};
  f32x4 ctx[4];
  float lrow = 0.f;  // lane-local partial row sum; reduced once after the loop
  #pragma unroll
  for (int dt = 0; dt < 4; dt++) ctx[dt] = zero4;

  __syncthreads();  // drains stage(0)'s global_load_lds + barrier

  for (int t = 0; t < 32; t++) {
    const int bi = t & 1;
    if (t < 31) stage(t + 1, bi ^ 1);  // overlaps compute; drained at iter end

    // QK^T (swapped + row-permuted): ST[mt][reg] = logit[q][m=kvb+(mt>>1)*32+g*8+(mt&1)*4+reg]
    f32x4 ST[4];
    #pragma unroll
    for (int mt = 0; mt < 4; mt++) ST[mt] = zero4;
    #pragma unroll
    for (int ks = 0; ks < 2; ks++) {
      #pragma unroll
      for (int mt = 0; mt < 4; mt++) {
        int mr = (mt >> 1) * 32 + (l15 >> 2) * 8 + (mt & 1) * 4 + e01;  // permuted A-row
        int pc = (ks * 4 + g) ^ (e01 | (a0 << 2));
        bf16x8 af = *(const bf16x8*)(&k_sm[bi][mr][pc * 8]);
        ST[mt] = mfma16(af, qf[ks], ST[mt]);
      }
    }
    #pragma unroll
    for (int mt = 0; mt < 4; mt++) {  // ext kstep: bias+mask rank-12 columns
      int mr = (mt >> 1) * 32 + (l15 >> 2) * 8 + (mt & 1) * 4 + e01;
      bf16x8 af = *(const bf16x8*)(&ke_sm[bi][mr][(g ^ e01) * 8]);
      ST[mt] = mfma16(af, qfe, ST[mt]);
    }

    // softmax: pv = 2^ST (logit already includes bias+mask, log2 domain, bounded)
    float pv[4][4];
    #pragma unroll
    for (int mt = 0; mt < 4; mt++) {
      pv[mt][0] = exp2_(ST[mt][0]);
      pv[mt][1] = exp2_(ST[mt][1]);
      pv[mt][2] = exp2_(ST[mt][2]);
      pv[mt][3] = exp2_(ST[mt][3]);
      lrow += pv[mt][0] + pv[mt][1] + pv[mt][2] + pv[mt][3];
    }
    bf16x8 pf[2];
    {
      union { unsigned u[4]; bf16x8 v; } pk0, pk1;
      pk0.u[0] = cvt_pk_bf16(pv[0][0], pv[0][1]);
      pk0.u[1] = cvt_pk_bf16(pv[0][2], pv[0][3]);
      pk0.u[2] = cvt_pk_bf16(pv[1][0], pv[1][1]);
      pk0.u[3] = cvt_pk_bf16(pv[1][2], pv[1][3]);
      pk1.u[0] = cvt_pk_bf16(pv[2][0], pv[2][1]);
      pk1.u[1] = cvt_pk_bf16(pv[2][2], pv[2][3]);
      pk1.u[2] = cvt_pk_bf16(pv[3][0], pv[3][1]);
      pk1.u[3] = cvt_pk_bf16(pv[3][2], pv[3][3]);
      pf[0] = pk0.v;
      pf[1] = pk1.v;
    }

    // PV: ctx[dt] += V^T-frag x P-frag (P in regs)
    #pragma unroll
    for (int kp = 0; kp < 2; kp++) {
      #pragma unroll
      for (int dt = 0; dt < 4; dt++) {
        int d = dt * 16 + l15;
        int pc = (kp * 4 + g) ^ (e01 | (((l15 >> 3) & 1) << 2));
        bf16x8 vf = *(const bf16x8*)(&vt_sm[bi][d][pc * 8]);
        ctx[dt] = mfma16(vf, pf[kp], ctx[dt]);
      }
    }

    // drains stage(t+1) and orders this tile's reads before next overwrite of buf bi
    __syncthreads();
  }

  // final row-sum reduction across the 4 g-lanes holding row q
  lrow += __shfl_xor(lrow, 16);
  lrow += __shfl_xor(lrow, 32);
  float inv = 1.0f / lrow;
  float* op = out + ((size_t)(b * 2048 + q)) * 1024 + h * 64 + g * 4;
  #pragma unroll
  for (int dt = 0; dt < 4; dt++) {
    float4 o = {ctx[dt][0] * inv, ctx[dt][1] * inv, ctx[dt][2] * inv, ctx[dt][3] * inv};
    *(float4*)(op + dt * 16) = o;
  }
}

extern "C" void kernel_launch(void* const* d_in, const int* in_sizes, int n_in,
                              void* d_out, int out_size, void* d_ws, size_t ws_size,
                              hipStream_t stream) {
  const float* hidden = (const float*)d_in[0];
  const float* maskp  = (const float*)d_in[1];
  const float* Wq     = (const float*)d_in[2];
  const float* bq     = (const float*)d_in[3];
  const float* Wk     = (const float*)d_in[4];
  const float* bk     = (const float*)d_in[5];
  const float* Wv     = (const float*)d_in[6];
  const float* bv     = (const float*)d_in[7];
  const float* qpw    = (const float*)d_in[8];
  const float* kpw    = (const float*)d_in[9];
  const float* coef   = (const float*)d_in[10];

  char* ws = (char*)d_ws;
  ushort_t* keb   = (ushort_t*)(ws);                  // 2*2048*32*2 = 262,144
  ushort_t* hb    = (ushort_t*)(ws + 262144);         // 8,388,608
  ushort_t* w3    = (ushort_t*)(ws + 8650752);        // 6,291,456 (Q' / K / Wv bf16)
  float*    Ah    = (float*)(ws + 14942208);          // 262,144
  float*    bq2   = (float*)(ws + 15204352);          // 4,096
  ushort_t* qeb   = (ushort_t*)(ws + 15208448);       // 16*2048*32*2 = 2,097,152
  ushort_t* qkb   = (ushort_t*)(ws + 17305600);       // 4096*2048*2 = 16,777,216
  ushort_t* vTb   = (ushort_t*)(ws + 34082816);       // 32*64*2048*2 = 8,388,608 (end 42,471,424)

  k_prep<<<6352, 256, 0, stream>>>(hidden, Wk, Wv, qpw, kpw, coef, maskp,
                                   hb, w3, Ah, keb, qeb);
  k_wq<<<dim3(16, 16), 256, 0, stream>>>(Wq, Ah, bq, w3, bq2);
  k_gemm<<<768, 256, 0, stream>>>(hb, w3, bq2, bk, bv, qkb, vTb);
  k_attn<<<1024, 256, 0, stream>>>(qkb, vTb, qeb, keb, (float*)d_out);
}

// Round 19
// 135.792 us; speedup vs baseline: 1.1035x; 1.0271x over previous
//
#include <hip/hip_runtime.h>

// OrthogonalBasisSelfAttention: B=2, L=2048, D=1024, H=16, DH=64, R=512, NUM_BASIS=6
// scores = q.(Wqp Wkp^T/sqrt(R)).k^T -> fold A_h (x log2e) into Wq'; S = qt.k^T (K=64).
// DCT bias + mask folded as rank-12 columns (qe/ke) into QK^T (K=96); softmax = exp2(ST).
// R19: k_attn 8 waves/512 threads, 128 q-rows/block, grid 512 — each staged K/V/ke tile
// feeds 2x the q-rows (per-wave compute path identical to validated R15/R18).
// k_gemm BK=64 (R18), merged k_prep (R16), k_wq unchanged.

typedef unsigned short ushort_t;
typedef unsigned long long ull_t;
typedef __attribute__((ext_vector_type(8))) short bf16x8;   // 8 bf16 = 4 VGPR (MFMA A/B frag)
typedef __attribute__((ext_vector_type(4))) float f32x4;    // MFMA C/D frag

#define LOG2E 1.4426950408889634f
#define PI_F 3.14159265358979323846f

__device__ inline f32x4 mfma16(bf16x8 a, bf16x8 b, f32x4 c) {
  return __builtin_amdgcn_mfma_f32_16x16x32_bf16(a, b, c, 0, 0, 0);
}
__device__ inline void load_lds16(const void* g, void* l) {
  __builtin_amdgcn_global_load_lds((const __attribute__((address_space(1))) unsigned int*)g,
                                   (__attribute__((address_space(3))) unsigned int*)l, 16, 0, 0);
}
__device__ inline ushort_t f2bf(float f) {  // round-to-nearest-even
  union { float f; unsigned int u; } v; v.f = f;
  unsigned int u = v.u;
  return (ushort_t)((u + 0x7fffu + ((u >> 16) & 1u)) >> 16);
}
__device__ inline unsigned cvt_pk_bf16(float lo, float hi) {
  unsigned r;
  asm("v_cvt_pk_bf16_f32 %0, %1, %2" : "=v"(r) : "v"(lo), "v"(hi));
  return r;
}
#if __has_builtin(__builtin_amdgcn_exp2f)
__device__ inline float exp2_(float x) { return __builtin_amdgcn_exp2f(x); }
#else
__device__ inline float exp2_(float x) { return exp2f(x); }
#endif

// ---- k_prep: Ah (in-kernel kpw transpose, grid-front) + cvt + ke/qe tables ----
// blocks [0,64): Ah[h][d][d'] = sum_r qpw[h][d][r]*kpw[h][d'][r] * C  (r-chunked LDS transpose)
// blocks [64,6208): fp32->bf16 cvt (hidden / Wk / Wv)
// blocks [6208,6224): ke[b][m][32]; blocks [6224,6352): qe[h][q][32]
__global__ __launch_bounds__(256) void k_prep(
    const float* __restrict__ hidden, const float* __restrict__ Wk,
    const float* __restrict__ Wv, const float* __restrict__ qpw,
    const float* __restrict__ kpw, const float* __restrict__ coef,
    const float* __restrict__ maskp,
    ushort_t* __restrict__ hb, ushort_t* __restrict__ w3, float* __restrict__ Ah,
    ushort_t* __restrict__ ke, ushort_t* __restrict__ qe) {
  __shared__ float tile[64][65];
  const int blk = blockIdx.x, tid = threadIdx.x;
  if (blk < 64) {
    int h = blk >> 2, db = (blk & 3) * 16;
    int dp = tid & 63, d0 = db + (tid >> 6) * 4;
    float acc[4] = {0.f, 0.f, 0.f, 0.f};
    const float* kh = kpw + (size_t)h * 64 * 512;
    const float* qr = qpw + ((size_t)h * 64 + d0) * 512;
    for (int rc = 0; rc < 8; rc++) {
      __syncthreads();
      #pragma unroll
      for (int i = 0; i < 4; i++) {
        int idx = i * 256 + tid;              // 1024 float4 = 64 rows x 64 cols
        int d = idx >> 4, c4 = idx & 15;
        float4 v = *(const float4*)(kh + (size_t)d * 512 + rc * 64 + c4 * 4);
        *(float4*)(&tile[d][c4 * 4]) = v;
      }
      __syncthreads();
      for (int rr = 0; rr < 64; rr += 4) {
        float4 wk = *(const float4*)(&tile[dp][rr]);  // kpw[h][dp][rc*64+rr..+3]
        int r = rc * 64 + rr;
        #pragma unroll
        for (int i = 0; i < 4; i++) {
          float4 wq = *(const float4*)(qr + i * 512 + r);
          acc[i] += wq.x * wk.x + wq.y * wk.y + wq.z * wk.z + wq.w * wk.w;
        }
      }
    }
    #pragma unroll
    for (int i = 0; i < 4; i++)
      Ah[((size_t)h * 64 + d0 + i) * 64 + dp] = acc[i] * (0.044194173824159216f * LOG2E);
  } else if (blk < 6208) {
    const float* in;
    ushort_t* out;
    int base = blk - 64;
    if (base < 4096) { in = hidden; out = hb; }
    else if (base < 5120) { in = Wk; out = w3 + 1048576; base -= 4096; }
    else { in = Wv; out = w3 + 2097152; base -= 5120; }
    int i = (base * 256 + tid) * 4;
    float4 v = *(const float4*)(in + i);
    ull_t pk = (ull_t)f2bf(v.x) | ((ull_t)f2bf(v.y) << 16)
             | ((ull_t)f2bf(v.z) << 32) | ((ull_t)f2bf(v.w) << 48);
    *(ull_t*)(out + i) = pk;
  } else if (blk < 6224) {
    int i = (blk - 6208) * 256 + tid;      // 0..4095
    int bb = i >> 11, m = i & 2047;
    float base = PI_F * (float)m * (1.0f / 2047.0f);
    ushort_t row[32];
    row[0] = f2bf(1.0f);
    #pragma unroll
    for (int k = 1; k <= 5; k++) {
      float a = base * (float)k;
      row[2 * k - 1] = f2bf(cosf(a));
      row[2 * k]     = f2bf(sinf(a));
    }
    row[11] = f2bf(maskp[bb * 2048 + m] * LOG2E);
    #pragma unroll
    for (int j = 12; j < 32; j++) row[j] = 0;
    ull_t* dst = (ull_t*)(ke + ((size_t)(bb * 2048 + m)) * 32);
    #pragma unroll
    for (int j = 0; j < 4; j++) {
      ull_t pk = 0;
      #pragma unroll
      for (int e = 0; e < 4; e++) pk |= (ull_t)row[j * 4 + e] << (16 * e);
      dst[j] = pk;
    }
  } else {
    int i = (blk - 6224) * 256 + tid;      // 0..32767
    int h = i >> 11, q = i & 2047;
    float base = PI_F * (float)q * (1.0f / 2047.0f);
    ushort_t row[32];
    row[0] = f2bf(coef[h * 6] * LOG2E);
    #pragma unroll
    for (int k = 1; k <= 5; k++) {
      float ck = coef[h * 6 + k] * LOG2E;
      float a = base * (float)k;
      row[2 * k - 1] = f2bf(ck * cosf(a));
      row[2 * k]     = f2bf(ck * sinf(a));
    }
    row[11] = f2bf(1.0f);
    #pragma unroll
    for (int j = 12; j < 32; j++) row[j] = 0;
    ull_t* dst = (ull_t*)(qe + ((size_t)(h * 2048 + q)) * 32);
    #pragma unroll
    for (int j = 0; j < 4; j++) {
      ull_t pk = 0;
      #pragma unroll
      for (int e = 0; e < 4; e++) pk |= (ull_t)row[j * 4 + e] << (16 * e);
      dst[j] = pk;
    }
  }
}

// ---- W'[h*64+d'][:] = sum_d A_h[h][d][d'] * Wq[h*64+d][:]; bq2 = bq.Ah ----
__global__ __launch_bounds__(256) void k_wq(
    const float* __restrict__ Wq, const float* __restrict__ Ah,
    const float* __restrict__ bq, ushort_t* __restrict__ w3, float* __restrict__ bq2) {
  __shared__ float wq_s[64][65];
  __shared__ float ah_s[64][65];
  int h = blockIdx.y, ct = blockIdx.x;
  int t = threadIdx.x;
  #pragma unroll
  for (int i = 0; i < 16; i++) {
    int idx = i * 256 + t, r = idx >> 6, c = idx & 63;
    wq_s[r][c] = Wq[((size_t)h * 64 + r) * 1024 + ct * 64 + c];
    ah_s[r][c] = Ah[((size_t)h * 64 + r) * 64 + c];
  }
  __syncthreads();
  int dp = t >> 2, cg = (t & 3) * 16;
  float acc[16];
  #pragma unroll
  for (int j = 0; j < 16; j++) acc[j] = 0.f;
  for (int d = 0; d < 64; d++) {
    float a = ah_s[d][dp];
    #pragma unroll
    for (int j = 0; j < 16; j++) acc[j] += a * wq_s[d][cg + j];
  }
  ushort_t* orow = w3 + ((size_t)h * 64 + dp) * 1024 + ct * 64 + cg;
  #pragma unroll
  for (int j = 0; j < 16; j += 4) {
    ull_t pk = (ull_t)f2bf(acc[j]) | ((ull_t)f2bf(acc[j + 1]) << 16)
             | ((ull_t)f2bf(acc[j + 2]) << 32) | ((ull_t)f2bf(acc[j + 3]) << 48);
    *(ull_t*)(orow + j) = pk;
  }
  if (ct == 0 && t < 64) {
    float bsum = 0.f;
    for (int d = 0; d < 64; d++) bsum += bq[h * 64 + d] * ah_s[d][t];
    bq2[h * 64 + t] = bsum;
  }
}

// ---- fused GEMM (XCD-swizzled), BK=64: 32 MFMA per barrier pair (R18, validated) ----
__global__ __launch_bounds__(256) void k_gemm(
    const ushort_t* __restrict__ hb, const ushort_t* __restrict__ w3,
    const float* __restrict__ bq2, const float* __restrict__ bk,
    const float* __restrict__ bv, ushort_t* __restrict__ qk, ushort_t* __restrict__ vT) {
  __shared__ ushort_t Asm[128 * 64];   // 16 KB
  __shared__ ushort_t Bsm[128 * 64];   // 16 KB
  const int tid = threadIdx.x, w = tid >> 6, l = tid & 63, g = l >> 4, l15 = l & 15;
  const int raw = blockIdx.x;
  const int id = (raw & 7) * 96 + (raw >> 3);  // bijective XCD chunking (768 = 8*96)
  const bool isv = id >= 512;
  int bx, by;
  const ushort_t *Aptr, *Bptr;
  if (!isv) { bx = id & 31; by = id >> 5; Aptr = hb; Bptr = w3; }
  else { int id2 = id - 512; bx = id2 & 7; by = id2 >> 3; Aptr = w3 + 2048 * 1024; Bptr = hb; }
  const int mbase = bx * 128, nbase = by * 128;
  const int wrow = (w >> 1) * 64, wcol = (w & 1) * 64;
  f32x4 zero4 = {0.f, 0.f, 0.f, 0.f};
  f32x4 acc[4][4];
  #pragma unroll
  for (int i = 0; i < 4; i++)
    #pragma unroll
    for (int j = 0; j < 4; j++) acc[i][j] = zero4;

  for (int kt = 0; kt < 16; ++kt) {
    __syncthreads();
    #pragma unroll
    for (int i = 0; i < 4; i++) {
      int r0 = i * 32 + w * 8;          // wave writes rows r0..r0+7 (one 1KB slab)
      int r = r0 + (l >> 3);
      int cs = (l & 7) ^ (r & 7);       // pre-swizzled source chunk
      load_lds16(Aptr + (size_t)(mbase + r) * 1024 + kt * 64 + cs * 8, &Asm[r0 * 64]);
      load_lds16(Bptr + (size_t)(nbase + r) * 1024 + kt * 64 + cs * 8, &Bsm[r0 * 64]);
    }
    __syncthreads();
    #pragma unroll
    for (int ks = 0; ks < 2; ks++) {
      bf16x8 a[4], bfr[4];
      #pragma unroll
      for (int rt = 0; rt < 4; rt++) {
        int r = wrow + rt * 16 + l15;
        a[rt] = *(const bf16x8*)(&Asm[r * 64 + (((ks * 4 + g) ^ (r & 7)) << 3)]);
      }
      #pragma unroll
      for (int ct = 0; ct < 4; ct++) {
        int r = wcol + ct * 16 + l15;
        bfr[ct] = *(const bf16x8*)(&Bsm[r * 64 + (((ks * 4 + g) ^ (r & 7)) << 3)]);
      }
      #pragma unroll
      for (int rt = 0; rt < 4; rt++)
        #pragma unroll
        for (int ct = 0; ct < 4; ct++)
          acc[rt][ct] = mfma16(a[rt], bfr[ct], acc[rt][ct]);
    }
  }
  if (!isv) {
    #pragma unroll
    for (int ct = 0; ct < 4; ct++) {
      int n = nbase + wcol + ct * 16 + l15;
      float bias = (n < 1024) ? bq2[n] : bk[n - 1024];
      #pragma unroll
      for (int rt = 0; rt < 4; rt++)
        #pragma unroll
        for (int reg = 0; reg < 4; reg++) {
          int m = mbase + wrow + rt * 16 + g * 4 + reg;
          qk[(size_t)m * 2048 + n] = f2bf(acc[rt][ct][reg] + bias);
        }
    }
  } else {
    #pragma unroll
    for (int rt = 0; rt < 4; rt++)
      #pragma unroll
      for (int reg = 0; reg < 4; reg++) {
        int dg = mbase + wrow + rt * 16 + g * 4 + reg;
        float bias = bv[dg];
        ushort_t* vrow = vT + ((size_t)(dg >> 6)) * 131072 + (size_t)(dg & 63) * 2048;
        #pragma unroll
        for (int ct = 0; ct < 4; ct++) {
          int mg = nbase + wcol + ct * 16 + l15;
          vrow[((size_t)(mg >> 11)) * 2097152 + (mg & 2047)] = f2bf(acc[rt][ct][reg] + bias);
        }
      }
  }
}

// ---- flash attention, K=96, 8 waves x 16 q = 128 q/block, KVB=64, grid 512 ----
// Per-wave compute identical to R15/R18 (validated); staged K/V/ke tiles shared by
// 2x the q-rows. LDS 40KB, 2 blocks/CU (= 16 waves/CU). Softmax pv = exp2(ST).
__global__ __launch_bounds__(512, 4) void k_attn(
    const ushort_t* __restrict__ qk, const ushort_t* __restrict__ vT,
    const ushort_t* __restrict__ qe, const ushort_t* __restrict__ ke,
    float* __restrict__ out) {
  __shared__ ushort_t k_sm[2][64][64];    // 16 KB, phys chunk p holds global chunk p^f(m)
  __shared__ ushort_t vt_sm[2][64][64];   // 16 KB, same swizzle by d
  __shared__ ushort_t ke_sm[2][64][32];   // 8 KB, phys chunk c holds global chunk c^(m&3)
  const int tid = threadIdx.x, w = tid >> 6, l = tid & 63, g = l >> 4, l15 = l & 15;
  const int e01 = l15 & 3, a0 = (l15 >> 2) & 1;
  const int lr = l >> 3, lc = l & 7;
  // 512 blocks: each XCD owns 4 bh x 16 q-blocks of 128 rows (64 blocks/XCD, 2/CU)
  const int bid = blockIdx.x, xcd = bid & 7, slot = bid >> 3;
  const int bh = xcd * 4 + (slot & 3), qb = slot >> 2;
  const int b = bh >> 4, h = bh & 15;
  const int wrow = qb * 128 + w * 16;   // wave w owns q-rows wrow..wrow+15
  const int q = wrow + l15;

  const ushort_t* kbase = qk + 1024 + h * 64;  // + row*2048
  const ushort_t* vT_bh = vT + (size_t)bh * 64 * 2048;
  const ushort_t* ke_b = ke + (size_t)b * 2048 * 32;

  auto stage = [&](int t, int bi) {
    int kvb = t * 64;
    {  // k rows: wave w stages rows w*8..w*8+7 (128B each), 1 load16/lane
      int m = w * 8 + lr;
      int sc = lc ^ ((lr & 3) | ((w & 1) << 2));  // f(m): m&3 = lr&3, (m>>3)&1 = w&1
      load_lds16(kbase + (size_t)(b * 2048 + kvb + m) * 2048 + sc * 8,
                 &k_sm[bi][w * 8][0]);
    }
    {  // vT rows: same assignment by d
      int d = w * 8 + lr;
      int sc = lc ^ ((lr & 3) | ((w & 1) << 2));
      load_lds16(vT_bh + (size_t)d * 2048 + kvb + sc * 8,
                 &vt_sm[bi][w * 8][0]);
    }
    if (w < 4) {  // ke rows: waves 0-3 stage rows w*16..w*16+15 (64B each)
      int ml = l >> 2, c = l & 3;
      load_lds16(ke_b + (size_t)(kvb + w * 16 + ml) * 32 + ((c ^ (ml & 3)) << 3),
                 &ke_sm[bi][w * 16][0]);
    }
  };

  stage(0, 0);

  bf16x8 qf[2], qfe;
  {
    const ushort_t* qpr = qk + (size_t)(b * 2048 + q) * 2048 + h * 64 + g * 8;
    qf[0] = *(const bf16x8*)(qpr);
    qf[1] = *(const bf16x8*)(qpr + 32);
    qfe = *(const bf16x8*)(qe + ((size_t)(h * 2048 + q)) * 32 + g * 8);
  }

  f32x4 zero4 = {0.f, 0.f, 0.f, 0.f};
  f32x4 ctx[4];
  float lrow = 0.f;  // lane-local partial row sum; reduced once after the loop
  #pragma unroll
  for (int dt = 0; dt < 4; dt++) ctx[dt] = zero4;

  __syncthreads();  // drains stage(0)'s global_load_lds + barrier

  for (int t = 0; t < 32; t++) {
    const int bi = t & 1;
    if (t < 31) stage(t + 1, bi ^ 1);  // overlaps compute; drained at iter end

    // QK^T (swapped + row-permuted): ST[mt][reg] = logit[q][m=kvb+(mt>>1)*32+g*8+(mt&1)*4+reg]
    f32x4 ST[4];
    #pragma unroll
    for (int mt = 0; mt < 4; mt++) ST[mt] = zero4;
    #pragma unroll
    for (int ks = 0; ks < 2; ks++) {
      #pragma unroll
      for (int mt = 0; mt < 4; mt++) {
        int mr = (mt >> 1) * 32 + (l15 >> 2) * 8 + (mt & 1) * 4 + e01;  // permuted A-row
        int pc = (ks * 4 + g) ^ (e01 | (a0 << 2));
        bf16x8 af = *(const bf16x8*)(&k_sm[bi][mr][pc * 8]);
        ST[mt] = mfma16(af, qf[ks], ST[mt]);
      }
    }
    #pragma unroll
    for (int mt = 0; mt < 4; mt++) {  // ext kstep: bias+mask rank-12 columns
      int mr = (mt >> 1) * 32 + (l15 >> 2) * 8 + (mt & 1) * 4 + e01;
      bf16x8 af = *(const bf16x8*)(&ke_sm[bi][mr][(g ^ e01) * 8]);
      ST[mt] = mfma16(af, qfe, ST[mt]);
    }

    // softmax: pv = 2^ST (logit already includes bias+mask, log2 domain, bounded)
    float pv[4][4];
    #pragma unroll
    for (int mt = 0; mt < 4; mt++) {
      pv[mt][0] = exp2_(ST[mt][0]);
      pv[mt][1] = exp2_(ST[mt][1]);
      pv[mt][2] = exp2_(ST[mt][2]);
      pv[mt][3] = exp2_(ST[mt][3]);
      lrow += pv[mt][0] + pv[mt][1] + pv[mt][2] + pv[mt][3];
    }
    bf16x8 pf[2];
    {
      union { unsigned u[4]; bf16x8 v; } pk0, pk1;
      pk0.u[0] = cvt_pk_bf16(pv[0][0], pv[0][1]);
      pk0.u[1] = cvt_pk_bf16(pv[0][2], pv[0][3]);
      pk0.u[2] = cvt_pk_bf16(pv[1][0], pv[1][1]);
      pk0.u[3] = cvt_pk_bf16(pv[1][2], pv[1][3]);
      pk1.u[0] = cvt_pk_bf16(pv[2][0], pv[2][1]);
      pk1.u[1] = cvt_pk_bf16(pv[2][2], pv[2][3]);
      pk1.u[2] = cvt_pk_bf16(pv[3][0], pv[3][1]);
      pk1.u[3] = cvt_pk_bf16(pv[3][2], pv[3][3]);
      pf[0] = pk0.v;
      pf[1] = pk1.v;
    }

    // PV: ctx[dt] += V^T-frag x P-frag (P in regs)
    #pragma unroll
    for (int kp = 0; kp < 2; kp++) {
      #pragma unroll
      for (int dt = 0; dt < 4; dt++) {
        int d = dt * 16 + l15;
        int pc = (kp * 4 + g) ^ (e01 | (((l15 >> 3) & 1) << 2));
        bf16x8 vf = *(const bf16x8*)(&vt_sm[bi][d][pc * 8]);
        ctx[dt] = mfma16(vf, pf[kp], ctx[dt]);
      }
    }

    // drains stage(t+1) and orders this tile's reads before next overwrite of buf bi
    __syncthreads();
  }

  // final row-sum reduction across the 4 g-lanes holding row q
  lrow += __shfl_xor(lrow, 16);
  lrow += __shfl_xor(lrow, 32);
  float inv = 1.0f / lrow;
  float* op = out + ((size_t)(b * 2048 + q)) * 1024 + h * 64 + g * 4;
  #pragma unroll
  for (int dt = 0; dt < 4; dt++) {
    float4 o = {ctx[dt][0] * inv, ctx[dt][1] * inv, ctx[dt][2] * inv, ctx[dt][3] * inv};
    *(float4*)(op + dt * 16) = o;
  }
}

extern "C" void kernel_launch(void* const* d_in, const int* in_sizes, int n_in,
                              void* d_out, int out_size, void* d_ws, size_t ws_size,
                              hipStream_t stream) {
  const float* hidden = (const float*)d_in[0];
  const float* maskp  = (const float*)d_in[1];
  const float* Wq     = (const float*)d_in[2];
  const float* bq     = (const float*)d_in[3];
  const float* Wk     = (const float*)d_in[4];
  const float* bk     = (const float*)d_in[5];
  const float* Wv     = (const float*)d_in[6];
  const float* bv     = (const float*)d_in[7];
  const float* qpw    = (const float*)d_in[8];
  const float* kpw    = (const float*)d_in[9];
  const float* coef   = (const float*)d_in[10];

  char* ws = (char*)d_ws;
  ushort_t* keb   = (ushort_t*)(ws);                  // 2*2048*32*2 = 262,144
  ushort_t* hb    = (ushort_t*)(ws + 262144);         // 8,388,608
  ushort_t* w3    = (ushort_t*)(ws + 8650752);        // 6,291,456 (Q' / K / Wv bf16)
  float*    Ah    = (float*)(ws + 14942208);          // 262,144
  float*    bq2   = (float*)(ws + 15204352);          // 4,096
  ushort_t* qeb   = (ushort_t*)(ws + 15208448);       // 16*2048*32*2 = 2,097,152
  ushort_t* qkb   = (ushort_t*)(ws + 17305600);       // 4096*2048*2 = 16,777,216
  ushort_t* vTb   = (ushort_t*)(ws + 34082816);       // 32*64*2048*2 = 8,388,608 (end 42,471,424)

  k_prep<<<6352, 256, 0, stream>>>(hidden, Wk, Wv, qpw, kpw, coef, maskp,
                                   hb, w3, Ah, keb, qeb);
  k_wq<<<dim3(16, 16), 256, 0, stream>>>(Wq, Ah, bq, w3, bq2);
  k_gemm<<<768, 256, 0, stream>>>(hb, w3, bq2, bk, bv, qkb, vTb);
  k_attn<<<512, 512, 0, stream>>>(qkb, vTb, qeb, keb, (float*)d_out);
}